// Round 18
// baseline (108.637 us; speedup 1.0000x reference)
//
#include <hip/hip_runtime.h>
#include <hip/hip_fp16.h>

#define N_NODES 100000
#define E_EDGES 1600000
#define NCLS 10

#define BW 256                       // bucket width in nodes
#define NB 391                       // ceil(N_NODES / BW)
#define EPB 4096                     // edges per binning block
#define NBLK_BIN 392                 // ceil(E_EDGES / EPB)
#define BUCK_CAP 6144                // max edges per bucket (mean 4096, std ~64)

// ------- blocks 0..391: per-block bucket histogram; block 392: W12,c1 -----
__global__ __launch_bounds__(256) void k_hist_w12(const int* __restrict__ col,
                                                  int* __restrict__ blockHist,
                                                  const float* __restrict__ W1,
                                                  const float* __restrict__ W2,
                                                  const float* __restrict__ b1,
                                                  float* __restrict__ W12,
                                                  float* __restrict__ c1) {
    __shared__ int   h[NB];
    __shared__ float w2s[1280];
    int t = threadIdx.x;
    if (blockIdx.x < NBLK_BIN) {
        for (int i = t; i < NB; i += 256) h[i] = 0;
        __syncthreads();
        int base = blockIdx.x * EPB;
        int end  = min(base + EPB, E_EDGES);
        for (int e = base + t; e < end; e += 256)
            atomicAdd(&h[col[e] >> 8], 1);
        __syncthreads();
        for (int i = t; i < NB; i += 256)
            blockHist[blockIdx.x * NB + i] = h[i];
    } else {
        for (int i = t; i < 1280; i += 256) w2s[i] = W2[i];
        __syncthreads();
        if (t < 128) {
            float acc[NCLS];
            #pragma unroll
            for (int j = 0; j < NCLS; ++j) acc[j] = 0.f;
            for (int m = 0; m < 128; ++m) {
                float w1mk = W1[m * 128 + t];    // coalesced column read
                #pragma unroll
                for (int j = 0; j < NCLS; ++j) acc[j] += w2s[j * 128 + m] * w1mk;
            }
            #pragma unroll
            for (int j = 0; j < NCLS; ++j) W12[j * 128 + t] = acc[j];
        } else if (t < 144) {
            int j = t - 128;
            float acc = 0.f;
            if (j < NCLS)
                for (int m = 0; m < 128; ++m) acc += W2[j * 128 + m] * b1[m];
            c1[j] = (j < NCLS) ? acc : 0.f;
        }
    }
}

// ------- parallel per-bucket column scan over the 392 block counts --------
__global__ __launch_bounds__(512) void k_colscan(int* __restrict__ blockHist,
                                                 int* __restrict__ bucketTotal) {
    __shared__ int s[512];
    int i = blockIdx.x;
    int t = threadIdx.x;
    int v = (t < NBLK_BIN) ? blockHist[t * NB + i] : 0;
    s[t] = v;
    __syncthreads();
    for (int st = 1; st < 512; st <<= 1) {
        int tmp = (t >= st) ? s[t - st] : 0;
        __syncthreads();
        s[t] += tmp;
        __syncthreads();
    }
    if (t < NBLK_BIN) blockHist[t * NB + i] = s[t] - v;   // exclusive
    if (t == 511) bucketTotal[i] = s[511];
}

// ------- blocks 0..391: bin edges via LDS staging (coalesced out) ---------
// ------- blocks 392..587: g1u = x @ W12^T (unscaled f32, pad 16) ----------
__global__ __launch_bounds__(512) void k_bin_g1(const int* __restrict__ ei,
                                                const int* __restrict__ blockHist,
                                                const int* __restrict__ bucketTotal,
                                                unsigned* __restrict__ binned,
                                                const float* __restrict__ x,
                                                const float* __restrict__ W12,
                                                float* __restrict__ g1u) {
    __shared__ int h[NB];
    __shared__ int lofs[NB];
    __shared__ int chunk[NB];
    __shared__ int s[512];
    __shared__ unsigned staged[EPB];
    int t = threadIdx.x;
    if (blockIdx.x < NBLK_BIN) {
        if (t < NB) h[t] = 0;
        __syncthreads();
        int base = blockIdx.x * EPB;
        int end  = min(base + EPB, E_EDGES);
        const int* col = ei + E_EDGES;
        // pass 1: local bucket histogram (8 iterations)
        for (int e = base + t; e < end; e += 512)
            atomicAdd(&h[col[e] >> 8], 1);
        __syncthreads();
        // scan local hist -> lofs (exclusive)
        int hv = (t < NB) ? h[t] : 0;
        s[t] = hv;
        __syncthreads();
        for (int st = 1; st < 512; st <<= 1) {
            int tmp = (t >= st) ? s[t - st] : 0;
            __syncthreads();
            s[t] += tmp;
            __syncthreads();
        }
        if (t < NB) lofs[t] = s[t] - hv;
        __syncthreads();
        // scan bucketTotal -> global chunk base for this block
        int bv = (t < NB) ? bucketTotal[t] : 0;
        s[t] = bv;
        __syncthreads();
        for (int st = 1; st < 512; st <<= 1) {
            int tmp = (t >= st) ? s[t - st] : 0;
            __syncthreads();
            s[t] += tmp;
            __syncthreads();
        }
        if (t < NB) {
            chunk[t] = (s[t] - bv) + blockHist[blockIdx.x * NB + t];
            h[t] = 0;    // reuse as cursor
        }
        __syncthreads();
        // pass 2: scatter into LDS staged (ordered by bucket, local rank)
        for (int e = base + t; e < end; e += 512) {
            int c = col[e];
            int r = ei[e];
            int b = c >> 8;
            int rank = atomicAdd(&h[b], 1);
            staged[lofs[b] + rank] = ((unsigned)r << 8) | (unsigned)(c & 255);
        }
        __syncthreads();
        // write out: per wave per bucket, coalesced contiguous runs
        int wid  = t >> 6;
        int lane = t & 63;
        for (int b = wid; b < NB; b += 8) {
            int lo  = lofs[b];
            int len = h[b];
            int gb  = chunk[b];
            for (int i = lane; i < len; i += 64)
                binned[gb + i] = staged[lo + i];
        }
    } else {
        int row = (blockIdx.x - NBLK_BIN) * 512 + t;
        if (row >= N_NODES) return;

        const float4* x4 = (const float4*)x;
        float acc[NCLS];
        #pragma unroll
        for (int j = 0; j < NCLS; ++j) acc[j] = 0.f;

        #pragma unroll
        for (int k4 = 0; k4 < 32; ++k4) {
            float4 xv = x4[row * 32 + k4];
            #pragma unroll
            for (int j = 0; j < NCLS; ++j) {
                const float* wj = &W12[j * 128 + k4 * 4];   // uniform -> s_load
                acc[j] += xv.x * wj[0] + xv.y * wj[1] + xv.z * wj[2] + xv.w * wj[3];
            }
        }

        float4* dst = (float4*)&g1u[row * 16];
        dst[0] = make_float4(acc[0], acc[1], acc[2], acc[3]);
        dst[1] = make_float4(acc[4], acc[5], acc[6], acc[7]);
        dst[2] = make_float4(acc[8], acc[9], 0.f, 0.f);
    }
}

// ------- per-bucket: degrees, offsets, dis, csr (LDS-staged) + g1 scale ---
__global__ __launch_bounds__(256) void k_build(const unsigned* __restrict__ binned,
                                               const int* __restrict__ bucketTotal,
                                               int2* __restrict__ od,
                                               float* __restrict__ dis,
                                               int* __restrict__ csr,
                                               const float* __restrict__ g1u,
                                               __half2* __restrict__ g1h) {
    __shared__ int red[256];
    __shared__ int cnt[BW];
    __shared__ int sc[BW];
    __shared__ int eoff[BW];
    __shared__ int cur[BW];
    __shared__ int stg[BUCK_CAP];
    int k = blockIdx.x;
    int t = threadIdx.x;

    int part = 0;
    for (int i = t; i < k; i += 256) part += bucketTotal[i];
    red[t] = part;
    cnt[t] = 0;
    __syncthreads();
    for (int st = 128; st; st >>= 1) {
        if (t < st) red[t] += red[t + st];
        __syncthreads();
    }
    int s0 = red[0];
    int s1 = s0 + bucketTotal[k];

    for (int i = s0 + t; i < s1; i += 256)
        atomicAdd(&cnt[binned[i] & 255], 1);
    __syncthreads();
    int v = cnt[t];
    sc[t] = v;
    __syncthreads();
    for (int st = 1; st < 256; st <<= 1) {
        int tmp = (t >= st) ? sc[t - st] : 0;
        __syncthreads();
        sc[t] += tmp;
        __syncthreads();
    }
    eoff[t] = sc[t] - v;   // exclusive
    cur[t] = 0;
    int node = k * BW + t;
    float d = rsqrtf((float)(v + 1));
    if (node < N_NODES) {
        od[node] = make_int2(s0 + eoff[t], v);
        dis[node] = d;

        // scale + pack g1: g1h[node] = fp16(d * g1u[node])
        const float4* g4 = (const float4*)&g1u[node * 16];
        float4 a = g4[0];
        float4 b = g4[1];
        float4 c = g4[2];
        __half2 hp[8];
        hp[0] = __floats2half2_rn(d * a.x, d * a.y);
        hp[1] = __floats2half2_rn(d * a.z, d * a.w);
        hp[2] = __floats2half2_rn(d * b.x, d * b.y);
        hp[3] = __floats2half2_rn(d * b.z, d * b.w);
        hp[4] = __floats2half2_rn(d * c.x, d * c.y);
        hp[5] = __floats2half2_rn(0.f, 0.f);
        hp[6] = hp[5];
        hp[7] = hp[5];
        uint4* dst = (uint4*)&g1h[node * 8];
        dst[0] = *(const uint4*)&hp[0];
        dst[1] = *(const uint4*)&hp[4];
    }
    __syncthreads();
    // scatter r into LDS by (node, rank); then coalesced copy to csr
    for (int i = s0 + t; i < s1; i += 256) {
        unsigned p = binned[i];
        int lc = p & 255;
        int r  = p >> 8;
        int pos = eoff[lc] + atomicAdd(&cur[lc], 1);
        stg[pos] = r;
    }
    __syncthreads();
    int len = s1 - s0;
    for (int i = t; i < len; i += 256)
        csr[s0 + i] = stg[i];
}

// ------- agg A: h2h = fp16( dc*(dc*acc + c1) ), acc = sum of scaled rows --
// 8-lane groups; 4-deep rotating prefetch of csr indices.
__global__ __launch_bounds__(256) void k_agg_a(const __half2* __restrict__ g1h,
                                               const float* __restrict__ dis,
                                               const int* __restrict__ csr,
                                               const int2* __restrict__ od,
                                               const float* __restrict__ c1,
                                               __half2* __restrict__ h2h) {
    int c = blockIdx.x * 32 + (threadIdx.x >> 3);
    int j = threadIdx.x & 7;
    if (c >= N_NODES) return;

    float2 acc = __half22float2(g1h[c * 8 + j]);   // self (pre-scaled)

    int2 odv  = od[c];
    int start = odv.x;
    int deg   = odv.y;
    int k = 0;
    if (deg >= 4) {
        int i0 = csr[start + 0], i1 = csr[start + 1];
        int i2 = csr[start + 2], i3 = csr[start + 3];
        for (; k + 8 <= deg; k += 4) {
            int n0 = csr[start + k + 4], n1 = csr[start + k + 5];
            int n2 = csr[start + k + 6], n3 = csr[start + k + 7];
            float2 a0 = __half22float2(g1h[i0 * 8 + j]);
            float2 a1 = __half22float2(g1h[i1 * 8 + j]);
            float2 a2 = __half22float2(g1h[i2 * 8 + j]);
            float2 a3 = __half22float2(g1h[i3 * 8 + j]);
            acc.x += (a0.x + a1.x) + (a2.x + a3.x);
            acc.y += (a0.y + a1.y) + (a2.y + a3.y);
            i0 = n0; i1 = n1; i2 = n2; i3 = n3;
        }
        float2 a0 = __half22float2(g1h[i0 * 8 + j]);
        float2 a1 = __half22float2(g1h[i1 * 8 + j]);
        float2 a2 = __half22float2(g1h[i2 * 8 + j]);
        float2 a3 = __half22float2(g1h[i3 * 8 + j]);
        acc.x += (a0.x + a1.x) + (a2.x + a3.x);
        acc.y += (a0.y + a1.y) + (a2.y + a3.y);
        k += 4;
    }
    for (; k < deg; ++k) {
        float2 a = __half22float2(g1h[csr[start + k] * 8 + j]);
        acc.x += a.x;
        acc.y += a.y;
    }

    float dc = dis[c];
    float ox = dc * (dc * acc.x + c1[2 * j]);       // j>=5: acc=0,c1=0 -> 0
    float oy = dc * (dc * acc.y + c1[2 * j + 1]);
    h2h[c * 8 + j] = __floats2half2_rn(ox, oy);
}

// ------- agg B: out = dc*acc + b2 (compact N x 10 f32 output) -------------
__global__ __launch_bounds__(256) void k_agg_b(const __half2* __restrict__ h2h,
                                               const float* __restrict__ dis,
                                               const int* __restrict__ csr,
                                               const int2* __restrict__ od,
                                               const float* __restrict__ b2,
                                               float* __restrict__ out) {
    int c = blockIdx.x * 32 + (threadIdx.x >> 3);
    int j = threadIdx.x & 7;
    if (c >= N_NODES) return;

    float2 acc = __half22float2(h2h[c * 8 + j]);   // self (pre-scaled)

    int2 odv  = od[c];
    int start = odv.x;
    int deg   = odv.y;
    int k = 0;
    if (deg >= 4) {
        int i0 = csr[start + 0], i1 = csr[start + 1];
        int i2 = csr[start + 2], i3 = csr[start + 3];
        for (; k + 8 <= deg; k += 4) {
            int n0 = csr[start + k + 4], n1 = csr[start + k + 5];
            int n2 = csr[start + k + 6], n3 = csr[start + k + 7];
            float2 a0 = __half22float2(h2h[i0 * 8 + j]);
            float2 a1 = __half22float2(h2h[i1 * 8 + j]);
            float2 a2 = __half22float2(h2h[i2 * 8 + j]);
            float2 a3 = __half22float2(h2h[i3 * 8 + j]);
            acc.x += (a0.x + a1.x) + (a2.x + a3.x);
            acc.y += (a0.y + a1.y) + (a2.y + a3.y);
            i0 = n0; i1 = n1; i2 = n2; i3 = n3;
        }
        float2 a0 = __half22float2(h2h[i0 * 8 + j]);
        float2 a1 = __half22float2(h2h[i1 * 8 + j]);
        float2 a2 = __half22float2(h2h[i2 * 8 + j]);
        float2 a3 = __half22float2(h2h[i3 * 8 + j]);
        acc.x += (a0.x + a1.x) + (a2.x + a3.x);
        acc.y += (a0.y + a1.y) + (a2.y + a3.y);
        k += 4;
    }
    for (; k < deg; ++k) {
        float2 a = __half22float2(h2h[csr[start + k] * 8 + j]);
        acc.x += a.x;
        acc.y += a.y;
    }

    if (j < 5) {
        float dc = dis[c];
        float2 o;
        o.x = dc * acc.x + b2[2 * j];
        o.y = dc * acc.y + b2[2 * j + 1];
        *(float2*)&out[c * NCLS + 2 * j] = o;
    }
}

extern "C" void kernel_launch(void* const* d_in, const int* in_sizes, int n_in,
                              void* d_out, int out_size, void* d_ws, size_t ws_size,
                              hipStream_t stream) {
    const float* x  = (const float*)d_in[0];
    const int*   ei = (const int*)d_in[1];   // [2, E] int32
    const float* W1 = (const float*)d_in[2];
    const float* b1 = (const float*)d_in[3];
    const float* W2 = (const float*)d_in[4];
    const float* b2 = (const float*)d_in[5];
    float* out = (float*)d_out;

    char* ws = (char*)d_ws;
    int*      bucketTotal = (int*)(ws + 8192);              // NB ints
    float*    W12         = (float*)(ws + 16384);           // 5 KB
    float*    c1          = (float*)(ws + 24576);           // 64 B (16 padded)
    int*      blockHist   = (int*)(ws + 32768);             // 392*391 ints ~613 KB
    int2*     od          = (int2*)(ws + (1 << 20));        // 800 KB
    float*    dis         = (float*)(ws + (3 << 20));       // 400 KB
    unsigned* binned      = (unsigned*)(ws + (4 << 20));    // 6.4 MB
    int*      csr         = (int*)(ws + (12 << 20));        // 6.4 MB
    float*    g1u         = (float*)(ws + (20 << 20));      // 6.4 MB (f32 x16)
    __half2*  g1h         = (__half2*)(ws + (28 << 20));    // 3.2 MB
    __half2*  h2h         = (__half2*)(ws + (32 << 20));    // 3.2 MB

    k_hist_w12<<<NBLK_BIN + 1, 256, 0, stream>>>(ei + E_EDGES, blockHist,
                                                 W1, W2, b1, W12, c1);
    k_colscan<<<NB, 512, 0, stream>>>(blockHist, bucketTotal);
    k_bin_g1<<<NBLK_BIN + 196, 512, 0, stream>>>(ei, blockHist, bucketTotal,
                                                 binned, x, W12, g1u);
    k_build<<<NB, 256, 0, stream>>>(binned, bucketTotal, od, dis, csr, g1u, g1h);

    k_agg_a<<<(N_NODES + 31) / 32, 256, 0, stream>>>(g1h, dis, csr, od, c1, h2h);
    k_agg_b<<<(N_NODES + 31) / 32, 256, 0, stream>>>(h2h, dis, csr, od, b2, out);
}

// Round 20
// 90.605 us; speedup vs baseline: 1.1990x; 1.1990x over previous
//
#include <hip/hip_runtime.h>
#include <hip/hip_fp16.h>

#define N_NODES 100000
#define E_EDGES 1600000
#define NCLS 10

#define BW 512                       // bucket width in nodes
#define NB 196                       // ceil(N_NODES / BW)
#define EPB 8192                     // edges per binning block
#define NBLK_BIN 196                 // ceil(E_EDGES / EPB)
#define BUCK_CAP 9216                // max edges per bucket (mean 8192, std ~90)
#define E4 (E_EDGES / 4)             // 400000 int4 edges

// ------- blocks 0..195: per-block bucket histogram; block 196: W12,c1 -----
__global__ __launch_bounds__(256) void k_hist_w12(const int* __restrict__ col,
                                                  int* __restrict__ blockHist,
                                                  const float* __restrict__ W1,
                                                  const float* __restrict__ W2,
                                                  const float* __restrict__ b1,
                                                  float* __restrict__ W12,
                                                  float* __restrict__ c1) {
    __shared__ int   h[NB];
    __shared__ float w2s[1280];
    int t = threadIdx.x;
    if (blockIdx.x < NBLK_BIN) {
        if (t < NB) h[t] = 0;
        __syncthreads();
        const int4* col4 = (const int4*)col;
        int base4 = blockIdx.x * (EPB / 4);
        int end4  = min(base4 + EPB / 4, E4);
        for (int e4 = base4 + t; e4 < end4; e4 += 256) {
            int4 cv = col4[e4];
            atomicAdd(&h[cv.x >> 9], 1);
            atomicAdd(&h[cv.y >> 9], 1);
            atomicAdd(&h[cv.z >> 9], 1);
            atomicAdd(&h[cv.w >> 9], 1);
        }
        __syncthreads();
        if (t < NB) blockHist[blockIdx.x * NB + t] = h[t];
    } else {
        for (int i = t; i < 1280; i += 256) w2s[i] = W2[i];
        __syncthreads();
        if (t < 128) {
            float acc[NCLS];
            #pragma unroll
            for (int j = 0; j < NCLS; ++j) acc[j] = 0.f;
            for (int m = 0; m < 128; ++m) {
                float w1mk = W1[m * 128 + t];    // coalesced column read
                #pragma unroll
                for (int j = 0; j < NCLS; ++j) acc[j] += w2s[j * 128 + m] * w1mk;
            }
            #pragma unroll
            for (int j = 0; j < NCLS; ++j) W12[j * 128 + t] = acc[j];
        } else if (t < 144) {
            int j = t - 128;
            float acc = 0.f;
            if (j < NCLS)
                for (int m = 0; m < 128; ++m) acc += W2[j * 128 + m] * b1[m];
            c1[j] = (j < NCLS) ? acc : 0.f;
        }
    }
}

// ------- parallel per-bucket column scan over the 196 block counts --------
__global__ __launch_bounds__(256) void k_colscan(int* __restrict__ blockHist,
                                                 int* __restrict__ bucketTotal) {
    __shared__ int s[256];
    int i = blockIdx.x;
    int t = threadIdx.x;
    int v = (t < NBLK_BIN) ? blockHist[t * NB + i] : 0;
    s[t] = v;
    __syncthreads();
    for (int st = 1; st < 256; st <<= 1) {
        int tmp = (t >= st) ? s[t - st] : 0;
        __syncthreads();
        s[t] += tmp;
        __syncthreads();
    }
    if (t < NBLK_BIN) blockHist[t * NB + i] = s[t] - v;   // exclusive
    if (t == 255) bucketTotal[i] = s[255];
}

// ------- blocks 0..195: bin edges via LDS staging (coalesced out) ---------
// ------- blocks 196..391: g1u = x @ W12^T (unscaled f32, pad 16) ----------
__global__ __launch_bounds__(512) void k_bin_g1(const int* __restrict__ ei,
                                                const int* __restrict__ blockHist,
                                                const int* __restrict__ bucketTotal,
                                                unsigned* __restrict__ binned,
                                                const float* __restrict__ x,
                                                const float* __restrict__ W12,
                                                float* __restrict__ g1u) {
    __shared__ int h[NB];
    __shared__ int lofs[NB];
    __shared__ int chunk[NB];
    __shared__ int s[512];
    __shared__ unsigned staged[EPB];
    int t = threadIdx.x;
    if (blockIdx.x < NBLK_BIN) {
        if (t < NB) h[t] = 0;
        __syncthreads();
        const int4* col4 = (const int4*)(ei + E_EDGES);
        const int4* row4 = (const int4*)ei;
        int base4 = blockIdx.x * (EPB / 4);
        int end4  = min(base4 + EPB / 4, E4);
        // pass 1: local bucket histogram (int4)
        for (int e4 = base4 + t; e4 < end4; e4 += 512) {
            int4 cv = col4[e4];
            atomicAdd(&h[cv.x >> 9], 1);
            atomicAdd(&h[cv.y >> 9], 1);
            atomicAdd(&h[cv.z >> 9], 1);
            atomicAdd(&h[cv.w >> 9], 1);
        }
        __syncthreads();
        // merged dual scan: seg0 (t<256) = local hist, seg1 = bucketTotal
        int u = t & 255;
        int v;
        if (t < 256) v = (u < NB) ? h[u] : 0;
        else         v = (u < NB) ? bucketTotal[u] : 0;
        s[t] = v;
        __syncthreads();
        for (int st = 1; st <= 128; st <<= 1) {
            int tmp = (u >= st) ? s[t - st] : 0;
            __syncthreads();
            s[t] += tmp;
            __syncthreads();
        }
        if (t < 256) {
            if (u < NB) lofs[u] = s[t] - v;                // local exclusive
        } else if (u < NB) {
            chunk[u] = (s[t] - v) + blockHist[blockIdx.x * NB + u];
        }
        __syncthreads();
        if (t < NB) h[t] = 0;    // reuse as cursor
        __syncthreads();
        // pass 2: scatter into LDS staged (bucket-major, rank order)
        for (int e4 = base4 + t; e4 < end4; e4 += 512) {
            int4 cv = col4[e4];
            int4 rv = row4[e4];
            int b0 = cv.x >> 9;
            staged[lofs[b0] + atomicAdd(&h[b0], 1)] =
                ((unsigned)rv.x << 9) | (unsigned)(cv.x & 511);
            int b1 = cv.y >> 9;
            staged[lofs[b1] + atomicAdd(&h[b1], 1)] =
                ((unsigned)rv.y << 9) | (unsigned)(cv.y & 511);
            int b2 = cv.z >> 9;
            staged[lofs[b2] + atomicAdd(&h[b2], 1)] =
                ((unsigned)rv.z << 9) | (unsigned)(cv.z & 511);
            int b3 = cv.w >> 9;
            staged[lofs[b3] + atomicAdd(&h[b3], 1)] =
                ((unsigned)rv.w << 9) | (unsigned)(cv.w & 511);
        }
        __syncthreads();
        // write out: per wave per bucket, coalesced contiguous runs (~42)
        int wid  = t >> 6;
        int lane = t & 63;
        for (int b = wid; b < NB; b += 8) {
            int lo  = lofs[b];
            int len = h[b];
            int gb  = chunk[b];
            for (int i = lane; i < len; i += 64)
                binned[gb + i] = staged[lo + i];
        }
    } else {
        int row = (blockIdx.x - NBLK_BIN) * 512 + t;
        if (row >= N_NODES) return;

        const float4* x4 = (const float4*)x;
        float acc[NCLS];
        #pragma unroll
        for (int j = 0; j < NCLS; ++j) acc[j] = 0.f;

        #pragma unroll
        for (int k4 = 0; k4 < 32; ++k4) {
            float4 xv = x4[row * 32 + k4];
            #pragma unroll
            for (int j = 0; j < NCLS; ++j) {
                const float* wj = &W12[j * 128 + k4 * 4];   // uniform -> s_load
                acc[j] += xv.x * wj[0] + xv.y * wj[1] + xv.z * wj[2] + xv.w * wj[3];
            }
        }

        float4* dst = (float4*)&g1u[row * 16];
        dst[0] = make_float4(acc[0], acc[1], acc[2], acc[3]);
        dst[1] = make_float4(acc[4], acc[5], acc[6], acc[7]);
        dst[2] = make_float4(acc[8], acc[9], 0.f, 0.f);
    }
}

// ------- per-bucket: degrees, offsets, dis, csr (LDS-staged) + g1 scale ---
__global__ __launch_bounds__(512) void k_build(const unsigned* __restrict__ binned,
                                               const int* __restrict__ bucketTotal,
                                               int2* __restrict__ od,
                                               float* __restrict__ dis,
                                               int* __restrict__ csr,
                                               const float* __restrict__ g1u,
                                               __half2* __restrict__ g1h) {
    __shared__ int red[512];
    __shared__ int cnt[BW];
    __shared__ int sc[BW];
    __shared__ int eoff[BW];
    __shared__ int cur[BW];
    __shared__ int stg[BUCK_CAP];
    int k = blockIdx.x;
    int t = threadIdx.x;

    red[t] = (t < k) ? bucketTotal[t] : 0;   // k < 196 < 512
    cnt[t] = 0;
    __syncthreads();
    for (int st = 256; st; st >>= 1) {
        if (t < st) red[t] += red[t + st];
        __syncthreads();
    }
    int s0 = red[0];
    int s1 = s0 + bucketTotal[k];

    for (int i = s0 + t; i < s1; i += 512)
        atomicAdd(&cnt[binned[i] & 511], 1);
    __syncthreads();
    int v = cnt[t];
    sc[t] = v;
    __syncthreads();
    for (int st = 1; st < 512; st <<= 1) {
        int tmp = (t >= st) ? sc[t - st] : 0;
        __syncthreads();
        sc[t] += tmp;
        __syncthreads();
    }
    eoff[t] = sc[t] - v;   // exclusive
    cur[t] = 0;
    int node = k * BW + t;
    float d = rsqrtf((float)(v + 1));
    if (node < N_NODES) {
        od[node] = make_int2(s0 + eoff[t], v);
        dis[node] = d;

        // scale + pack g1: g1h[node] = fp16(d * g1u[node])
        const float4* g4 = (const float4*)&g1u[node * 16];
        float4 a = g4[0];
        float4 b = g4[1];
        float4 c = g4[2];
        __half2 hp[8];
        hp[0] = __floats2half2_rn(d * a.x, d * a.y);
        hp[1] = __floats2half2_rn(d * a.z, d * a.w);
        hp[2] = __floats2half2_rn(d * b.x, d * b.y);
        hp[3] = __floats2half2_rn(d * b.z, d * b.w);
        hp[4] = __floats2half2_rn(d * c.x, d * c.y);
        hp[5] = __floats2half2_rn(0.f, 0.f);
        hp[6] = hp[5];
        hp[7] = hp[5];
        uint4* dst = (uint4*)&g1h[node * 8];
        dst[0] = *(const uint4*)&hp[0];
        dst[1] = *(const uint4*)&hp[4];
    }
    __syncthreads();
    // scatter r into LDS by (node, rank); then coalesced copy to csr
    for (int i = s0 + t; i < s1; i += 512) {
        unsigned p = binned[i];
        int lc = p & 511;
        int r  = p >> 9;
        int pos = eoff[lc] + atomicAdd(&cur[lc], 1);
        stg[pos] = r;
    }
    __syncthreads();
    int len = s1 - s0;
    for (int i = t; i < len; i += 512)
        csr[s0 + i] = stg[i];
}

// ------- agg A: h2h = fp16( dc*(dc*acc + c1) ), acc = sum of scaled rows --
// 8-lane groups; 4-deep rotating prefetch of csr indices.
__global__ __launch_bounds__(256) void k_agg_a(const __half2* __restrict__ g1h,
                                               const float* __restrict__ dis,
                                               const int* __restrict__ csr,
                                               const int2* __restrict__ od,
                                               const float* __restrict__ c1,
                                               __half2* __restrict__ h2h) {
    int c = blockIdx.x * 32 + (threadIdx.x >> 3);
    int j = threadIdx.x & 7;
    if (c >= N_NODES) return;

    float2 acc = __half22float2(g1h[c * 8 + j]);   // self (pre-scaled)

    int2 odv  = od[c];
    int start = odv.x;
    int deg   = odv.y;
    int k = 0;
    if (deg >= 4) {
        int i0 = csr[start + 0], i1 = csr[start + 1];
        int i2 = csr[start + 2], i3 = csr[start + 3];
        for (; k + 8 <= deg; k += 4) {
            int n0 = csr[start + k + 4], n1 = csr[start + k + 5];
            int n2 = csr[start + k + 6], n3 = csr[start + k + 7];
            float2 a0 = __half22float2(g1h[i0 * 8 + j]);
            float2 a1 = __half22float2(g1h[i1 * 8 + j]);
            float2 a2 = __half22float2(g1h[i2 * 8 + j]);
            float2 a3 = __half22float2(g1h[i3 * 8 + j]);
            acc.x += (a0.x + a1.x) + (a2.x + a3.x);
            acc.y += (a0.y + a1.y) + (a2.y + a3.y);
            i0 = n0; i1 = n1; i2 = n2; i3 = n3;
        }
        float2 a0 = __half22float2(g1h[i0 * 8 + j]);
        float2 a1 = __half22float2(g1h[i1 * 8 + j]);
        float2 a2 = __half22float2(g1h[i2 * 8 + j]);
        float2 a3 = __half22float2(g1h[i3 * 8 + j]);
        acc.x += (a0.x + a1.x) + (a2.x + a3.x);
        acc.y += (a0.y + a1.y) + (a2.y + a3.y);
        k += 4;
    }
    for (; k < deg; ++k) {
        float2 a = __half22float2(g1h[csr[start + k] * 8 + j]);
        acc.x += a.x;
        acc.y += a.y;
    }

    float dc = dis[c];
    float ox = dc * (dc * acc.x + c1[2 * j]);       // j>=5: acc=0,c1=0 -> 0
    float oy = dc * (dc * acc.y + c1[2 * j + 1]);
    h2h[c * 8 + j] = __floats2half2_rn(ox, oy);
}

// ------- agg B: out = dc*acc + b2 (compact N x 10 f32 output) -------------
__global__ __launch_bounds__(256) void k_agg_b(const __half2* __restrict__ h2h,
                                               const float* __restrict__ dis,
                                               const int* __restrict__ csr,
                                               const int2* __restrict__ od,
                                               const float* __restrict__ b2,
                                               float* __restrict__ out) {
    int c = blockIdx.x * 32 + (threadIdx.x >> 3);
    int j = threadIdx.x & 7;
    if (c >= N_NODES) return;

    float2 acc = __half22float2(h2h[c * 8 + j]);   // self (pre-scaled)

    int2 odv  = od[c];
    int start = odv.x;
    int deg   = odv.y;
    int k = 0;
    if (deg >= 4) {
        int i0 = csr[start + 0], i1 = csr[start + 1];
        int i2 = csr[start + 2], i3 = csr[start + 3];
        for (; k + 8 <= deg; k += 4) {
            int n0 = csr[start + k + 4], n1 = csr[start + k + 5];
            int n2 = csr[start + k + 6], n3 = csr[start + k + 7];
            float2 a0 = __half22float2(h2h[i0 * 8 + j]);
            float2 a1 = __half22float2(h2h[i1 * 8 + j]);
            float2 a2 = __half22float2(h2h[i2 * 8 + j]);
            float2 a3 = __half22float2(h2h[i3 * 8 + j]);
            acc.x += (a0.x + a1.x) + (a2.x + a3.x);
            acc.y += (a0.y + a1.y) + (a2.y + a3.y);
            i0 = n0; i1 = n1; i2 = n2; i3 = n3;
        }
        float2 a0 = __half22float2(h2h[i0 * 8 + j]);
        float2 a1 = __half22float2(h2h[i1 * 8 + j]);
        float2 a2 = __half22float2(h2h[i2 * 8 + j]);
        float2 a3 = __half22float2(h2h[i3 * 8 + j]);
        acc.x += (a0.x + a1.x) + (a2.x + a3.x);
        acc.y += (a0.y + a1.y) + (a2.y + a3.y);
        k += 4;
    }
    for (; k < deg; ++k) {
        float2 a = __half22float2(h2h[csr[start + k] * 8 + j]);
        acc.x += a.x;
        acc.y += a.y;
    }

    if (j < 5) {
        float dc = dis[c];
        float2 o;
        o.x = dc * acc.x + b2[2 * j];
        o.y = dc * acc.y + b2[2 * j + 1];
        *(float2*)&out[c * NCLS + 2 * j] = o;
    }
}

extern "C" void kernel_launch(void* const* d_in, const int* in_sizes, int n_in,
                              void* d_out, int out_size, void* d_ws, size_t ws_size,
                              hipStream_t stream) {
    const float* x  = (const float*)d_in[0];
    const int*   ei = (const int*)d_in[1];   // [2, E] int32
    const float* W1 = (const float*)d_in[2];
    const float* b1 = (const float*)d_in[3];
    const float* W2 = (const float*)d_in[4];
    const float* b2 = (const float*)d_in[5];
    float* out = (float*)d_out;

    char* ws = (char*)d_ws;
    int*      bucketTotal = (int*)(ws + 8192);              // NB ints
    float*    W12         = (float*)(ws + 16384);           // 5 KB
    float*    c1          = (float*)(ws + 24576);           // 64 B (16 padded)
    int*      blockHist   = (int*)(ws + 32768);             // 196*196 ints ~154 KB
    int2*     od          = (int2*)(ws + (1 << 20));        // 800 KB
    float*    dis         = (float*)(ws + (3 << 20));       // 400 KB
    unsigned* binned      = (unsigned*)(ws + (4 << 20));    // 6.4 MB
    int*      csr         = (int*)(ws + (12 << 20));        // 6.4 MB
    float*    g1u         = (float*)(ws + (20 << 20));      // 6.4 MB (f32 x16)
    __half2*  g1h         = (__half2*)(ws + (28 << 20));    // 3.2 MB
    __half2*  h2h         = (__half2*)(ws + (32 << 20));    // 3.2 MB

    k_hist_w12<<<NBLK_BIN + 1, 256, 0, stream>>>(ei + E_EDGES, blockHist,
                                                 W1, W2, b1, W12, c1);
    k_colscan<<<NB, 256, 0, stream>>>(blockHist, bucketTotal);
    k_bin_g1<<<NBLK_BIN + 196, 512, 0, stream>>>(ei, blockHist, bucketTotal,
                                                 binned, x, W12, g1u);
    k_build<<<NB, 512, 0, stream>>>(binned, bucketTotal, od, dis, csr, g1u, g1h);

    k_agg_a<<<(N_NODES + 31) / 32, 256, 0, stream>>>(g1h, dis, csr, od, c1, h2h);
    k_agg_b<<<(N_NODES + 31) / 32, 256, 0, stream>>>(h2h, dis, csr, od, b2, out);
}